// Round 1
// baseline (594.390 us; speedup 1.0000x reference)
//
#include <hip/hip_runtime.h>
#include <hip/hip_bf16.h>

#define D 128
#define K 8
#define BGRAPH 64

// ---------------------------------------------------------------------------
// Stage 1: fused edge linear + GINE message + scatter-add
//   agg[dst] += relu(x[src] + edge_attr @ We + be)
// 2 edges per 256-thread block iteration; We/be staged in LDS.
// ---------------------------------------------------------------------------
__global__ __launch_bounds__(256) void edge_kernel(
    const float* __restrict__ x, const int* __restrict__ src,
    const int* __restrict__ dst, const float* __restrict__ ea,
    const float* __restrict__ We, const float* __restrict__ be,
    float* __restrict__ agg, int E)
{
    __shared__ float sWe[16 * D];
    __shared__ float sbe[D];
    for (int i = threadIdx.x; i < 16 * D; i += 256) sWe[i] = We[i];
    if (threadIdx.x < D) sbe[threadIdx.x] = be[threadIdx.x];
    __syncthreads();

    const int d    = threadIdx.x & (D - 1);
    const int half = threadIdx.x >> 7;          // 0 or 1: which edge of the pair

    for (int e = blockIdx.x * 2 + half; e < E; e += gridDim.x * 2) {
        const int s = src[e];
        const int t = dst[e];
        const float4* ea4 = (const float4*)(ea + (size_t)e * 16);
        const float4 a0 = ea4[0], a1 = ea4[1], a2 = ea4[2], a3 = ea4[3];
        float acc = sbe[d];
        acc += a0.x * sWe[ 0 * D + d] + a0.y * sWe[ 1 * D + d]
             + a0.z * sWe[ 2 * D + d] + a0.w * sWe[ 3 * D + d];
        acc += a1.x * sWe[ 4 * D + d] + a1.y * sWe[ 5 * D + d]
             + a1.z * sWe[ 6 * D + d] + a1.w * sWe[ 7 * D + d];
        acc += a2.x * sWe[ 8 * D + d] + a2.y * sWe[ 9 * D + d]
             + a2.z * sWe[10 * D + d] + a2.w * sWe[11 * D + d];
        acc += a3.x * sWe[12 * D + d] + a3.y * sWe[13 * D + d]
             + a3.z * sWe[14 * D + d] + a3.w * sWe[15 * D + d];
        float m = x[(size_t)s * D + d] + acc;
        m = m > 0.0f ? m : 0.0f;
        atomicAdd(&agg[(size_t)t * D + d], m);
    }
}

// ---------------------------------------------------------------------------
// Stage 2: fused 2-layer MLP on h = (1+eps)*x + agg
//   x_res = relu(h @ W1 + b1) @ W2 + b2
// 32 rows per block; h and t tiles in LDS; per-thread 16-row accumulator.
// ---------------------------------------------------------------------------
#define MLP_RB 32
__global__ __launch_bounds__(256) void mlp_kernel(
    const float* __restrict__ x, const float* __restrict__ agg,
    const float* __restrict__ epsp,
    const float* __restrict__ W1, const float* __restrict__ b1,
    const float* __restrict__ W2, const float* __restrict__ b2,
    float* __restrict__ xres, int N)
{
    __shared__ float sh[MLP_RB * D];
    __shared__ float st[MLP_RB * D];
    const int row0 = blockIdx.x * MLP_RB;
    const float ep = 1.0f + epsp[0];

    // Phase A: build h tile in LDS (float4)
    for (int i = threadIdx.x; i < MLP_RB * D / 4; i += 256) {
        const int idx = i * 4;
        const int r = idx >> 7;
        const int c = idx & (D - 1);
        const int row = row0 + r;
        float4 hv;
        if (row < N) {
            const float4 xv = *(const float4*)(x   + (size_t)row * D + c);
            const float4 av = *(const float4*)(agg + (size_t)row * D + c);
            hv = make_float4(ep * xv.x + av.x, ep * xv.y + av.y,
                             ep * xv.z + av.z, ep * xv.w + av.w);
        } else {
            hv = make_float4(0.f, 0.f, 0.f, 0.f);
        }
        *(float4*)(sh + idx) = hv;
    }
    __syncthreads();

    const int d  = threadIdx.x & (D - 1);
    const int rg = threadIdx.x >> 7;   // 0 or 1 -> rows [rg*16, rg*16+16)
    float acc[16];

    // Layer 1: t = relu(h @ W1 + b1)
    {
        const float bb = b1[d];
        #pragma unroll
        for (int r = 0; r < 16; ++r) acc[r] = bb;
        for (int k = 0; k < D; k += 4) {
            const float w0 = W1[(k + 0) * D + d];
            const float w1 = W1[(k + 1) * D + d];
            const float w2 = W1[(k + 2) * D + d];
            const float w3 = W1[(k + 3) * D + d];
            #pragma unroll
            for (int r = 0; r < 16; ++r) {
                const float4 h4 = *(const float4*)(sh + (rg * 16 + r) * D + k);
                acc[r] += h4.x * w0 + h4.y * w1 + h4.z * w2 + h4.w * w3;
            }
        }
        #pragma unroll
        for (int r = 0; r < 16; ++r)
            st[(rg * 16 + r) * D + d] = acc[r] > 0.0f ? acc[r] : 0.0f;
    }
    __syncthreads();

    // Layer 2: x_res = t @ W2 + b2
    {
        const float bb = b2[d];
        #pragma unroll
        for (int r = 0; r < 16; ++r) acc[r] = bb;
        for (int k = 0; k < D; k += 4) {
            const float w0 = W2[(k + 0) * D + d];
            const float w1 = W2[(k + 1) * D + d];
            const float w2 = W2[(k + 2) * D + d];
            const float w3 = W2[(k + 3) * D + d];
            #pragma unroll
            for (int r = 0; r < 16; ++r) {
                const float4 t4 = *(const float4*)(st + (rg * 16 + r) * D + k);
                acc[r] += t4.x * w0 + t4.y * w1 + t4.z * w2 + t4.w * w3;
            }
        }
        #pragma unroll
        for (int r = 0; r < 16; ++r) {
            const int row = row0 + rg * 16 + r;
            if (row < N) xres[(size_t)row * D + d] = acc[r];
        }
    }
}

// ---------------------------------------------------------------------------
// Stage 3: per-(graph,pocket) masked sums. batch is sorted -> binary-search
// the contiguous node range of each graph; 4 blocks per graph, register
// accumulators, one atomicAdd per partial.
// ---------------------------------------------------------------------------
#define PPARTS 4
__global__ __launch_bounds__(128) void pocket_sum_kernel(
    const float* __restrict__ xres, const float* __restrict__ pmask,
    const int* __restrict__ batch,
    float* __restrict__ psum, float* __restrict__ pcnt, int N)
{
    const int g = blockIdx.x / PPARTS;
    const int part = blockIdx.x % PPARTS;

    // lower_bound(batch, g) and lower_bound(batch, g+1)
    int lo, hi;
    {
        int l = 0, r = N;
        while (l < r) { int m = (l + r) >> 1; if (batch[m] < g) l = m + 1; else r = m; }
        lo = l;
        r = N;
        while (l < r) { int m = (l + r) >> 1; if (batch[m] < g + 1) l = m + 1; else r = m; }
        hi = l;
    }
    const int cnt = hi - lo;
    const int per = (cnt + PPARTS - 1) / PPARTS;
    const int s = lo + part * per;
    const int e = min(s + per, hi);

    const int d = threadIdx.x;
    float acc[K];
    #pragma unroll
    for (int k = 0; k < K; ++k) acc[k] = 0.0f;
    float c = 0.0f;

    for (int n = s; n < e; ++n) {
        const float xv = xres[(size_t)n * D + d];
        const float4 m0 = *(const float4*)(pmask + (size_t)n * K);
        const float4 m1 = *(const float4*)(pmask + (size_t)n * K + 4);
        acc[0] += m0.x * xv; acc[1] += m0.y * xv;
        acc[2] += m0.z * xv; acc[3] += m0.w * xv;
        acc[4] += m1.x * xv; acc[5] += m1.y * xv;
        acc[6] += m1.z * xv; acc[7] += m1.w * xv;
        if (d < K) c += pmask[(size_t)n * K + d];
    }
    #pragma unroll
    for (int k = 0; k < K; ++k)
        atomicAdd(&psum[(size_t)g * (K * D) + k * D + d], acc[k]);
    if (d < K) atomicAdd(&pcnt[g * K + d], c);
}

// ---------------------------------------------------------------------------
// Stage 4: pocket_emb = (psum / (pcnt + 1e-9)) @ Wv + bv   (per graph)
// ---------------------------------------------------------------------------
__global__ __launch_bounds__(128) void pocket_emb_kernel(
    const float* __restrict__ psum, const float* __restrict__ pcnt,
    const float* __restrict__ Wv, const float* __restrict__ bv,
    float* __restrict__ pemb)
{
    __shared__ float smean[K * D];
    __shared__ float scnt[K];
    const int g = blockIdx.x;
    const int d = threadIdx.x;
    if (d < K) scnt[d] = pcnt[g * K + d];
    __syncthreads();
    #pragma unroll
    for (int k = 0; k < K; ++k)
        smean[k * D + d] = psum[(size_t)g * (K * D) + k * D + d] / (scnt[k] + 1e-9f);
    __syncthreads();

    float acc[K];
    const float bvv = bv[d];
    #pragma unroll
    for (int k = 0; k < K; ++k) acc[k] = bvv;
    for (int j = 0; j < D; ++j) {
        const float w = Wv[j * D + d];
        #pragma unroll
        for (int k = 0; k < K; ++k) acc[k] += smean[k * D + j] * w;
    }
    #pragma unroll
    for (int k = 0; k < K; ++k)
        pemb[(size_t)g * (K * D) + k * D + d] = acc[k];
}

// ---------------------------------------------------------------------------
// Stage 5: feedback gather + LayerNorm + ReLU. One wave per node, float2/lane,
// two-pass shuffle-reduce LN (exact population variance).
// ---------------------------------------------------------------------------
__global__ __launch_bounds__(256) void ln_kernel(
    const float* __restrict__ xres, const float* __restrict__ pmask,
    const int* __restrict__ batch, const float* __restrict__ pemb,
    const float* __restrict__ gamma, const float* __restrict__ beta,
    float* __restrict__ out, int N)
{
    const int wave = threadIdx.x >> 6;
    const int lane = threadIdx.x & 63;
    const int n = blockIdx.x * 4 + wave;
    if (n >= N) return;
    const int d = lane * 2;

    float2 v = *(const float2*)(xres + (size_t)n * D + d);
    const int g = batch[n];
    const float* pe = pemb + (size_t)g * (K * D);
    const float4 m0 = *(const float4*)(pmask + (size_t)n * K);
    const float4 m1 = *(const float4*)(pmask + (size_t)n * K + 4);
    const float mk[K] = {m0.x, m0.y, m0.z, m0.w, m1.x, m1.y, m1.z, m1.w};
    #pragma unroll
    for (int k = 0; k < K; ++k) {
        if (mk[k] != 0.0f) {   // wave-uniform branch (same n across the wave)
            const float2 p = *(const float2*)(pe + k * D + d);
            v.x += mk[k] * p.x;
            v.y += mk[k] * p.y;
        }
    }

    float s = v.x + v.y;
    #pragma unroll
    for (int off = 32; off; off >>= 1) s += __shfl_xor(s, off, 64);
    const float mu = s * (1.0f / 128.0f);
    const float d0 = v.x - mu, d1 = v.y - mu;
    float sq = d0 * d0 + d1 * d1;
    #pragma unroll
    for (int off = 32; off; off >>= 1) sq += __shfl_xor(sq, off, 64);
    const float var = sq * (1.0f / 128.0f);
    const float inv = rsqrtf(var + 1e-5f);

    const float2 gm = *(const float2*)(gamma + d);
    const float2 bt = *(const float2*)(beta + d);
    float y0 = d0 * inv * gm.x + bt.x;
    float y1 = d1 * inv * gm.y + bt.y;
    y0 = y0 > 0.0f ? y0 : 0.0f;
    y1 = y1 > 0.0f ? y1 : 0.0f;
    *(float2*)(out + (size_t)n * D + d) = make_float2(y0, y1);
}

// ---------------------------------------------------------------------------
extern "C" void kernel_launch(void* const* d_in, const int* in_sizes, int n_in,
                              void* d_out, int out_size, void* d_ws, size_t ws_size,
                              hipStream_t stream)
{
    const float* x     = (const float*)d_in[0];
    const int*   ei    = (const int*)  d_in[1];
    const float* ea    = (const float*)d_in[2];
    const float* pmask = (const float*)d_in[3];
    const int*   batch = (const int*)  d_in[4];
    const float* We    = (const float*)d_in[5];
    const float* be    = (const float*)d_in[6];
    const float* W1    = (const float*)d_in[7];
    const float* b1    = (const float*)d_in[8];
    const float* W2    = (const float*)d_in[9];
    const float* b2    = (const float*)d_in[10];
    const float* epsp  = (const float*)d_in[11];
    const float* gamma = (const float*)d_in[12];
    const float* beta  = (const float*)d_in[13];
    const float* Wv    = (const float*)d_in[14];
    const float* bv    = (const float*)d_in[15];
    float* out = (float*)d_out;

    const int N = in_sizes[0] / D;     // 50000
    const int E = in_sizes[1] / 2;     // 600000

    float* agg  = (float*)d_ws;                       // N*D
    float* xres = agg  + (size_t)N * D;               // N*D
    float* psum = xres + (size_t)N * D;               // B*K*D
    float* pcnt = psum + (size_t)BGRAPH * K * D;      // B*K
    float* pemb = pcnt + (size_t)BGRAPH * K;          // B*K*D

    hipMemsetAsync(agg, 0, (size_t)N * D * sizeof(float), stream);
    hipMemsetAsync(psum, 0, (size_t)(BGRAPH * K * D + BGRAPH * K) * sizeof(float), stream);

    edge_kernel<<<4096, 256, 0, stream>>>(x, ei, ei + E, ea, We, be, agg, E);
    mlp_kernel<<<(N + MLP_RB - 1) / MLP_RB, 256, 0, stream>>>(
        x, agg, epsp, W1, b1, W2, b2, xres, N);
    pocket_sum_kernel<<<BGRAPH * PPARTS, 128, 0, stream>>>(
        xres, pmask, batch, psum, pcnt, N);
    pocket_emb_kernel<<<BGRAPH, 128, 0, stream>>>(psum, pcnt, Wv, bv, pemb);
    ln_kernel<<<(N + 3) / 4, 256, 0, stream>>>(
        xres, pmask, batch, pemb, gamma, beta, out, N);
}